// Round 1
// baseline (236.332 us; speedup 1.0000x reference)
//
#include <hip/hip_runtime.h>
#include <hip/hip_bf16.h>

typedef __attribute__((ext_vector_type(8))) short bf16x8;
typedef __attribute__((ext_vector_type(4))) float f32x4;

// ws layout (bytes):
//   WT   [576][192] bf16 @ 0        (221184 B)   WT[n][k] = W*(k,n)  (Wq|Wk|Wv)
//   WfcT [192][192] bf16 @ 221184   (73728 B)    WfcT[n][k] = Wfc[k][n]
//   bias [3][49][49] f32 @ 294912   (28812 B)    0=plain 1=+LOWER 2=+RIGHT

__device__ __forceinline__ short f2bf(float f) {
  unsigned u = __float_as_uint(f);
  unsigned r = (u + 0x7FFFu + ((u >> 16) & 1u)) >> 16;
  return (short)(unsigned short)r;
}

__global__ void prep_kernel(const float* __restrict__ Wq, const float* __restrict__ Wk,
                            const float* __restrict__ Wv, const float* __restrict__ Wfc,
                            const float* __restrict__ pos,
                            short* __restrict__ WT, short* __restrict__ WfcT,
                            float* __restrict__ biasTab) {
  int i0 = blockIdx.x * blockDim.x + threadIdx.x;
  int stride = gridDim.x * blockDim.x;
  for (int idx = i0; idx < 576 * 192; idx += stride) {
    int n = idx / 192, kk = idx - n * 192;
    const float* W = (n < 192) ? Wq : (n < 384) ? Wk : Wv;
    WT[idx] = f2bf(W[kk * 192 + (n % 192)]);
  }
  for (int idx = i0; idx < 192 * 192; idx += stride) {
    int n = idx / 192, kk = idx - n * 192;
    WfcT[idx] = f2bf(Wfc[kk * 192 + n]);
  }
  for (int idx = i0; idx < 3 * 2401; idx += stride) {
    int t = idx / 2401, r = idx - t * 2401;
    int q = r / 49, k = r - q * 49;
    int ri = k / 7 - q / 7 + 6;       // rel = idx[k] - idx[q] + 6
    int rj = k % 7 - q % 7 + 6;
    float v = pos[ri * 13 + rj];
    if (t == 1 && ((q >= 28) != (k >= 28))) v = -1e30f;          // LOWER mask
    if (t == 2 && ((q % 7 >= 4) != (k % 7 >= 4))) v = -1e30f;    // RIGHT mask
    biasTab[idx] = v;
  }
}

__launch_bounds__(384)
__global__ void swin_fused(const float* __restrict__ x,
                           const short* __restrict__ WT,
                           const short* __restrict__ WfcT,
                           const float* __restrict__ biasTab,
                           const float* __restrict__ bfc,
                           float* __restrict__ out) {
  // LDS: 9408*2 + 9888*2 + 12288*2 + 18816*2 = 100,800 B
  __shared__ short qf[9408];      // q[49][192] flat; later reused for attn-out
  __shared__ short kf[9888];      // k[49][192] flat + pad (B-frag cols 49..63 read past window 5)
  __shared__ short vT[12288];     // per-window transposed v: [6][32][64], k-padded with zeros
  __shared__ short plds[18816];   // per-wave P: [6][49][64]

  const int bid = blockIdx.x;
  const int b = bid >> 6;
  const int g = bid & 63;
  const int tid = threadIdx.x;
  const int wave = tid >> 6;
  const int lane = tid & 63;
  const int lrow = lane & 15;            // within-tile row/col
  const int lk8 = (lane >> 4) << 3;      // k-chunk base {0,8,16,24}
  const int lg4 = (lane >> 4) << 2;      // D-frag row base {0,4,8,12}

  const bf16x8 z8 = {0, 0, 0, 0, 0, 0, 0, 0};
  const f32x4 z4 = {0.f, 0.f, 0.f, 0.f};

  // zero vT pad rows (avoid NaN garbage entering PV through k-padding)
  for (int i = tid; i < 12288; i += 384) vT[i] = 0;
  __syncthreads();

  // ---------------- Phase 1: QKV = x_shifted(49 tok) @ [Wq|Wk|Wv]  (M=64pad,N=576,K=192)
  bf16x8 afrag[4][6];
  #pragma unroll
  for (int mt = 0; mt < 4; ++mt) {
    int row = mt * 16 + lrow;
    if (row < 49) {
      int t = g * 49 + row;
      int h = t / 56, w = t - h * 56;
      int hs = h + 3; if (hs >= 56) hs -= 56;        // roll(-3): shifted[h] = x[h+3]
      int ws2 = w + 3; if (ws2 >= 56) ws2 -= 56;
      const float* xr = x + ((b * 56 + hs) * 56 + ws2) * 192;
      #pragma unroll
      for (int ks = 0; ks < 6; ++ks) {
        const float* p = xr + 32 * ks + lk8;
        float4 f0 = *(const float4*)(p);
        float4 f1 = *(const float4*)(p + 4);
        bf16x8 a;
        a[0] = f2bf(f0.x); a[1] = f2bf(f0.y); a[2] = f2bf(f0.z); a[3] = f2bf(f0.w);
        a[4] = f2bf(f1.x); a[5] = f2bf(f1.y); a[6] = f2bf(f1.z); a[7] = f2bf(f1.w);
        afrag[mt][ks] = a;
      }
    } else {
      #pragma unroll
      for (int ks = 0; ks < 6; ++ks) afrag[mt][ks] = z8;
    }
  }

  #pragma unroll 1
  for (int nt = 0; nt < 6; ++nt) {
    int col = wave * 96 + nt * 16 + lrow;            // 0..575
    const short* wr = WT + col * 192 + lk8;
    f32x4 acc[4] = {z4, z4, z4, z4};
    #pragma unroll
    for (int ks = 0; ks < 6; ++ks) {
      bf16x8 bfrag = *(const bf16x8*)(wr + 32 * ks);
      #pragma unroll
      for (int mt = 0; mt < 4; ++mt)
        acc[mt] = __builtin_amdgcn_mfma_f32_16x16x32_bf16(afrag[mt][ks], bfrag, acc[mt], 0, 0, 0);
    }
    #pragma unroll
    for (int mt = 0; mt < 4; ++mt) {
      #pragma unroll
      for (int jj = 0; jj < 4; ++jj) {
        int rowD = mt * 16 + lg4 + jj;
        if (rowD < 49) {
          short v = f2bf(acc[mt][jj]);
          if (col < 192) {
            qf[rowD * 192 + col] = v;
          } else if (col < 384) {
            kf[rowD * 192 + col - 192] = v;
          } else {
            int flat = rowD * 192 + col - 384;       // position in [49][192] v-flat
            int win = flat / 1568;
            int rem = flat - win * 1568;
            vT[(win * 32 + (rem & 31)) * 64 + (rem >> 5)] = v;   // vT[win][d][kr]
          }
        }
      }
    }
  }
  __syncthreads();

  // ---------------- Phase 2: attention, wave j owns window j
  {
    const int j = wave;
    const short* qw = qf + j * 1568;
    const short* kw = kf + j * 1568;
    bf16x8 qa[4];
    #pragma unroll
    for (int mt = 0; mt < 4; ++mt) {
      int row = mt * 16 + lrow;
      qa[mt] = (row < 49) ? *(const bf16x8*)(qw + row * 32 + lk8) : z8;
    }
    bf16x8 kb[4];
    #pragma unroll
    for (int nt = 0; nt < 4; ++nt)
      kb[nt] = *(const bf16x8*)(kw + (nt * 16 + lrow) * 32 + lk8);

    f32x4 s[4][4];
    #pragma unroll
    for (int mt = 0; mt < 4; ++mt)
      #pragma unroll
      for (int nt = 0; nt < 4; ++nt)
        s[mt][nt] = __builtin_amdgcn_mfma_f32_16x16x32_bf16(qa[mt], kb[nt], z4, 0, 0, 0);

    int win = (g * 6 + j) & 63;
    const float* bt = biasTab + ((win >= 56) ? 2401 : (win == 7) ? 4802 : 0);
    #pragma unroll
    for (int mt = 0; mt < 4; ++mt)
      #pragma unroll
      for (int nt = 0; nt < 4; ++nt)
        #pragma unroll
        for (int jj = 0; jj < 4; ++jj) {
          int qr = mt * 16 + lg4 + jj;
          int kc = nt * 16 + lrow;
          float v;
          if (qr < 49 && kc < 49)
            v = s[mt][nt][jj] * 5.65685424949238f + bt[qr * 49 + kc];  // note: *sqrt(32)
          else
            v = -1e30f;
          s[mt][nt][jj] = v;
        }

    // register softmax per q-row (reduce over 4 nt frags + 16 lanes of the group)
    #pragma unroll
    for (int mt = 0; mt < 4; ++mt)
      #pragma unroll
      for (int jj = 0; jj < 4; ++jj) {
        float m = fmaxf(fmaxf(s[mt][0][jj], s[mt][1][jj]), fmaxf(s[mt][2][jj], s[mt][3][jj]));
        m = fmaxf(m, __shfl_xor(m, 1));
        m = fmaxf(m, __shfl_xor(m, 2));
        m = fmaxf(m, __shfl_xor(m, 4));
        m = fmaxf(m, __shfl_xor(m, 8));
        float e0 = __expf(s[mt][0][jj] - m);
        float e1 = __expf(s[mt][1][jj] - m);
        float e2 = __expf(s[mt][2][jj] - m);
        float e3 = __expf(s[mt][3][jj] - m);
        float sum = (e0 + e1) + (e2 + e3);
        sum += __shfl_xor(sum, 1);
        sum += __shfl_xor(sum, 2);
        sum += __shfl_xor(sum, 4);
        sum += __shfl_xor(sum, 8);
        float inv = 1.0f / sum;
        int qr = mt * 16 + lg4 + jj;
        if (qr < 49) {
          short* pr = plds + j * 3136 + qr * 64 + lrow;
          pr[0]  = f2bf(e0 * inv);
          pr[16] = f2bf(e1 * inv);
          pr[32] = f2bf(e2 * inv);
          pr[48] = f2bf(e3 * inv);
        }
      }
  }
  __syncthreads();

  {
    const int j = wave;
    // PV: out[49][32] = P[49][64pad] @ V[64pad][32]
    bf16x8 pa[4][2];
    #pragma unroll
    for (int mt = 0; mt < 4; ++mt) {
      int row = mt * 16 + lrow;
      #pragma unroll
      for (int ks = 0; ks < 2; ++ks)
        pa[mt][ks] = (row < 49) ? *(const bf16x8*)(plds + j * 3136 + row * 64 + ks * 32 + lk8) : z8;
    }
    bf16x8 vb[2][2];
    #pragma unroll
    for (int nt = 0; nt < 2; ++nt)
      #pragma unroll
      for (int ks = 0; ks < 2; ++ks)
        vb[nt][ks] = *(const bf16x8*)(vT + (j * 32 + nt * 16 + lrow) * 64 + ks * 32 + lk8);

    f32x4 o[4][2] = {{z4, z4}, {z4, z4}, {z4, z4}, {z4, z4}};
    #pragma unroll
    for (int ks = 0; ks < 2; ++ks)
      #pragma unroll
      for (int mt = 0; mt < 4; ++mt)
        #pragma unroll
        for (int nt = 0; nt < 2; ++nt)
          o[mt][nt] = __builtin_amdgcn_mfma_f32_16x16x32_bf16(pa[mt][ks], vb[nt][ks], o[mt][nt], 0, 0, 0);

    short* ow = qf + j * 1568;   // attn-out overwrites q (same flat positions)
    #pragma unroll
    for (int mt = 0; mt < 4; ++mt)
      #pragma unroll
      for (int nt = 0; nt < 2; ++nt)
        #pragma unroll
        for (int jj = 0; jj < 4; ++jj) {
          int qr = mt * 16 + lg4 + jj;
          if (qr < 49) ow[qr * 32 + nt * 16 + lrow] = f2bf(o[mt][nt][jj]);
        }
  }
  __syncthreads();

  // ---------------- Phase 3: out = attnout[49][192] @ Wfc + bfc, inverse roll
  bf16x8 oa[4][6];
  #pragma unroll
  for (int mt = 0; mt < 4; ++mt) {
    int row = mt * 16 + lrow;
    #pragma unroll
    for (int ks = 0; ks < 6; ++ks)
      oa[mt][ks] = (row < 49) ? *(const bf16x8*)(qf + row * 192 + ks * 32 + lk8) : z8;
  }
  #pragma unroll 1
  for (int nt = 0; nt < 2; ++nt) {
    int col = wave * 32 + nt * 16 + lrow;            // 0..191
    const short* wr = WfcT + col * 192 + lk8;
    f32x4 acc[4] = {z4, z4, z4, z4};
    #pragma unroll
    for (int ks = 0; ks < 6; ++ks) {
      bf16x8 bfrag = *(const bf16x8*)(wr + 32 * ks);
      #pragma unroll
      for (int mt = 0; mt < 4; ++mt)
        acc[mt] = __builtin_amdgcn_mfma_f32_16x16x32_bf16(oa[mt][ks], bfrag, acc[mt], 0, 0, 0);
    }
    float bias = bfc[col];
    #pragma unroll
    for (int mt = 0; mt < 4; ++mt)
      #pragma unroll
      for (int jj = 0; jj < 4; ++jj) {
        int qr = mt * 16 + lg4 + jj;
        if (qr < 49) {
          int t = g * 49 + qr;
          int h = t / 56, w = t - h * 56;
          int hd = h + 3; if (hd >= 56) hd -= 56;    // roll(+3): out[h+3] = pre[h]
          int wd = w + 3; if (wd >= 56) wd -= 56;
          out[(size_t)((b * 56 + hd) * 56 + wd) * 192 + col] = acc[mt][jj] + bias;
        }
      }
  }
}

extern "C" void kernel_launch(void* const* d_in, const int* in_sizes, int n_in,
                              void* d_out, int out_size, void* d_ws, size_t ws_size,
                              hipStream_t stream) {
  const float* x   = (const float*)d_in[0];
  const float* Wq  = (const float*)d_in[1];
  const float* Wk  = (const float*)d_in[2];
  const float* Wv  = (const float*)d_in[3];
  const float* Wfc = (const float*)d_in[4];
  const float* bfc = (const float*)d_in[5];
  const float* pos = (const float*)d_in[6];

  short* WT    = (short*)d_ws;
  short* WfcT  = (short*)((char*)d_ws + 221184);
  float* biasT = (float*)((char*)d_ws + 294912);

  hipLaunchKernelGGL(prep_kernel, dim3(128), dim3(256), 0, stream,
                     Wq, Wk, Wv, Wfc, pos, WT, WfcT, biasT);
  hipLaunchKernelGGL(swin_fused, dim3(2048), dim3(384), 0, stream,
                     x, WT, WfcT, biasT, bfc, (float*)d_out);
}